// Round 5
// baseline (461.257 us; speedup 1.0000x reference)
//
#include <hip/hip_runtime.h>

#define V_DIM 128000
#define K_TOP 50
#define CPB 8                       // chunk-blocks per row
#define CHUNK (V_DIM / CPB)         // 16000
#define CHUNK4 (CHUNK / 4)          // 4000
#define CAPB 64                     // per-chunk candidate cap (mean 21.6, 9 sigma margin)
#define ROWCAP (CPB * CAPB)         // 512
#define K1T 512
#define NBINS 2048
#define THRESH 3.0f                 // P(N(0,1)>3)=1.35e-3 -> E[row count]=173 >> 50

typedef float floatx4 __attribute__((ext_vector_type(4)));

struct __align__(16) RowParams { float thrv; int idxcut; float lnS; unsigned thr; };

__device__ __forceinline__ unsigned key_of(float x) {
    unsigned b = __float_as_uint(x);
    return b ^ (unsigned)((((int)b) >> 31) | 0x80000000);
}
__device__ __forceinline__ float val_of(unsigned u) {
    unsigned b = u ^ (unsigned)(((~(int)u) >> 31) | 0x80000000);
    return __uint_as_float(b);
}

// ---- Kernel 1: single-pass stream (exp-sum + threshold collect) + last-block select
__global__ __launch_bounds__(K1T)
void k1_scan_select(const float* __restrict__ x, uint2* __restrict__ cand,
                    unsigned* __restrict__ cnts, double* __restrict__ psum,
                    unsigned* __restrict__ rowctr, RowParams* __restrict__ params) {
    __shared__ double   wsum[K1T / 64];
    __shared__ unsigned s_cnt;
    __shared__ uint2    cl[ROWCAP];
    __shared__ unsigned hist[NBINS];      // fallback only
    __shared__ unsigned offs[CPB];
    __shared__ unsigned s_n, s_b1, s_thr;
    __shared__ int      s_e, s_idxcut, s_fb, s_last;

    const int t = threadIdx.x;
    const int bid = blockIdx.x;
    const int row = bid >> 3, ch = bid & (CPB - 1);
    const float4* __restrict__ x4 = (const float4*)(x + (size_t)row * V_DIM + ch * CHUNK);

    if (t == 0) s_cnt = 0;
    __syncthreads();

    // ---- single pass: exp partial + candidate collect ----
    uint2* __restrict__ my = cand + (size_t)bid * CAPB;
    const int ibase = ch * CHUNK;
    float lsum = 0.f;
    for (int j = t; j < CHUNK4; j += K1T) {
        float4 v = x4[j];
        lsum += __expf(v.x) + __expf(v.y) + __expf(v.z) + __expf(v.w);
        if (v.x > THRESH) { unsigned p = atomicAdd(&s_cnt, 1u); if (p < CAPB) my[p] = make_uint2(__float_as_uint(v.x), (unsigned)(ibase + 4 * j)); }
        if (v.y > THRESH) { unsigned p = atomicAdd(&s_cnt, 1u); if (p < CAPB) my[p] = make_uint2(__float_as_uint(v.y), (unsigned)(ibase + 4 * j + 1)); }
        if (v.z > THRESH) { unsigned p = atomicAdd(&s_cnt, 1u); if (p < CAPB) my[p] = make_uint2(__float_as_uint(v.z), (unsigned)(ibase + 4 * j + 2)); }
        if (v.w > THRESH) { unsigned p = atomicAdd(&s_cnt, 1u); if (p < CAPB) my[p] = make_uint2(__float_as_uint(v.w), (unsigned)(ibase + 4 * j + 3)); }
    }
    #pragma unroll
    for (int off = 32; off; off >>= 1) lsum += __shfl_down(lsum, off);
    if ((t & 63) == 0) wsum[t >> 6] = (double)lsum;
    __syncthreads();
    if (t == 0) {
        double d = 0.0;
        for (int w = 0; w < K1T / 64; ++w) d += wsum[w];   // fixed order: deterministic
        psum[bid] = d;
        cnts[bid] = s_cnt;                                  // raw; selector detects overflow
    }
    __syncthreads();

    // ---- publish, then elect the last-arriving block of this row ----
    __threadfence();                       // release: flush our global writes
    __syncthreads();
    if (t == 0) {
        unsigned old = atomicAdd(&rowctr[row], 1u);         // works from ANY start value
        s_last = ((old & (CPB - 1)) == (CPB - 1)) ? 1 : 0;  // (2^32 % 8 == 0: wrap-safe)
    }
    __syncthreads();
    if (!s_last) return;
    __threadfence();                       // acquire: discard stale cached lines

    // ---- gather candidates for the row ----
    const int base = row * CPB;
    if (t == 0) {
        unsigned o = 0; int fb = 0;
        for (int b = 0; b < CPB; ++b) {
            unsigned c = cnts[base + b];
            if (c > CAPB) fb = 1;
            offs[b] = o;
            o += (c < CAPB ? c : CAPB);
        }
        s_n = o;
        if (o < (unsigned)K_TOP) fb = 1;   // threshold too high for this row -> exact fallback
        s_fb = fb;
    }
    __syncthreads();
    unsigned n;
    if (!s_fb) {
        for (int b = 0; b < CPB; ++b) {
            const unsigned o = offs[b];
            const unsigned c = ((b + 1 < CPB) ? offs[b + 1] : s_n) - o;
            const uint2* __restrict__ src = cand + (size_t)(base + b) * CAPB;
            for (int j = t; j < (int)c; j += K1T) {
                uint2 e = src[j];
                cl[o + j] = make_uint2(e.x | 0x80000000u, e.y);  // positive float -> sortable key
            }
        }
        n = s_n;
        __syncthreads();
    } else {
        // exact fallback (never taken for N(0,1) data): full-row histogram select
        for (int i = t; i < NBINS; i += K1T) hist[i] = 0;
        if (t == 0) s_n = 0;
        __syncthreads();
        const float4* __restrict__ xr = (const float4*)(x + (size_t)row * V_DIM);
        for (int j = t; j < V_DIM / 4; j += K1T) {
            float4 v = xr[j];
            atomicAdd(&hist[key_of(v.x) >> 21], 1u);
            atomicAdd(&hist[key_of(v.y) >> 21], 1u);
            atomicAdd(&hist[key_of(v.z) >> 21], 1u);
            atomicAdd(&hist[key_of(v.w) >> 21], 1u);
        }
        __syncthreads();
        if (t == 0) {
            unsigned cum = 0; int b1 = 0;
            for (int b = NBINS - 1; b >= 0; --b) {
                if (cum + hist[b] >= (unsigned)K_TOP) { b1 = b; break; }
                cum += hist[b];
            }
            s_b1 = (unsigned)b1;
        }
        __syncthreads();
        const unsigned kmin = s_b1 << 21;   // bins >= b1 contain all of top-K
        for (int j = t; j < V_DIM / 4; j += K1T) {
            float4 v = xr[j];
            unsigned u0 = key_of(v.x), u1 = key_of(v.y), u2 = key_of(v.z), u3 = key_of(v.w);
            if (u0 >= kmin) { unsigned p = atomicAdd(&s_n, 1u); if (p < ROWCAP) cl[p] = make_uint2(u0, (unsigned)(4 * j)); }
            if (u1 >= kmin) { unsigned p = atomicAdd(&s_n, 1u); if (p < ROWCAP) cl[p] = make_uint2(u1, (unsigned)(4 * j + 1)); }
            if (u2 >= kmin) { unsigned p = atomicAdd(&s_n, 1u); if (p < ROWCAP) cl[p] = make_uint2(u2, (unsigned)(4 * j + 2)); }
            if (u3 >= kmin) { unsigned p = atomicAdd(&s_n, 1u); if (p < ROWCAP) cl[p] = make_uint2(u3, (unsigned)(4 * j + 3)); }
        }
        __syncthreads();
        n = (s_n < ROWCAP) ? s_n : ROWCAP;
    }

    // ---- exact rank-K select among cl[0..n): candidates contain all of top-K ----
    for (int j = t; j < (int)n; j += K1T) {
        unsigned uj = cl[j].x; int g = 0, eq = 0;
        for (int k = 0; k < (int)n; ++k) {
            unsigned uk = cl[k].x;
            g += (uk > uj) ? 1 : 0;
            eq += (uk == uj) ? 1 : 0;
        }
        if (g < K_TOP && K_TOP <= g + eq) { s_thr = uj; s_e = K_TOP - g; }
    }
    __syncthreads();
    const unsigned thr = s_thr; const int e = s_e;
    // e-th smallest index among ties (jax top_k masks lowest indices first)
    for (int j = t; j < (int)n; j += K1T) {
        if (cl[j].x == thr) {
            int ij = (int)cl[j].y, rank = 0;
            for (int k = 0; k < (int)n; ++k)
                rank += (cl[k].x == thr && (int)cl[k].y < ij) ? 1 : 0;
            if (rank == e - 1) s_idxcut = ij;
        }
    }
    __syncthreads();
    const int idxcut = s_idxcut;
    // S = sum(exp) over row minus masked contributions
    double ms = 0.0;
    for (int j = t; j < (int)n; j += K1T) {
        unsigned u = cl[j].x;
        if (u > thr || (u == thr && (int)cl[j].y <= idxcut))
            ms += exp((double)val_of(u));
    }
    #pragma unroll
    for (int off = 32; off; off >>= 1) ms += __shfl_down(ms, off);
    if ((t & 63) == 0) wsum[t >> 6] = ms;
    __syncthreads();
    if (t == 0) {
        double S = 0.0;
        for (int b = 0; b < CPB; ++b) S += psum[base + b];   // fixed order
        for (int w = 0; w < K1T / 64; ++w) S -= wsum[w];
        RowParams p; p.thrv = val_of(thr); p.idxcut = idxcut;
        p.lnS = (float)log(S); p.thr = thr;
        params[row] = p;
    }
}

// ---- Kernel 2: masked softmax write (float-compare fast path, nt stores) ----
__global__ __launch_bounds__(256, 4)
void k3_write(const float* __restrict__ x, const RowParams* __restrict__ params,
              float* __restrict__ out) {
    const int row = blockIdx.y;
    const int seg = blockIdx.x;                 // 32 segs x 1000 float4
    const int t = threadIdx.x;
    const RowParams p = params[row];
    const float thrv = p.thrv; const int idxcut = p.idxcut; const float lnS = p.lnS;
    const unsigned thr = p.thr;
    const bool use_f = (thrv != 0.0f);          // uniform; +-0 falls back to key compare
    const float4* __restrict__ x4 = (const float4*)(x + (size_t)row * V_DIM) + seg * 1000;
    floatx4* __restrict__ o4 = (floatx4*)(out + (size_t)row * V_DIM) + seg * 1000;
    const int ibase = seg * 4000;
    for (int j = t; j < 1000; j += 256) {
        float4 v = x4[j];
        floatx4 o;
        const int i0 = ibase + 4 * j;
        bool m0, m1, m2, m3;
        if (use_f) {
            m0 = (v.x > thrv) || (v.x == thrv && i0 <= idxcut);
            m1 = (v.y > thrv) || (v.y == thrv && i0 + 1 <= idxcut);
            m2 = (v.z > thrv) || (v.z == thrv && i0 + 2 <= idxcut);
            m3 = (v.w > thrv) || (v.w == thrv && i0 + 3 <= idxcut);
        } else {
            unsigned u0 = key_of(v.x), u1 = key_of(v.y), u2 = key_of(v.z), u3 = key_of(v.w);
            m0 = (u0 > thr) || (u0 == thr && i0 <= idxcut);
            m1 = (u1 > thr) || (u1 == thr && i0 + 1 <= idxcut);
            m2 = (u2 > thr) || (u2 == thr && i0 + 2 <= idxcut);
            m3 = (u3 > thr) || (u3 == thr && i0 + 3 <= idxcut);
        }
        o.x = m0 ? 0.f : __expf(v.x - lnS);
        o.y = m1 ? 0.f : __expf(v.y - lnS);
        o.z = m2 ? 0.f : __expf(v.z - lnS);
        o.w = m3 ? 0.f : __expf(v.w - lnS);
        __builtin_nontemporal_store(o, &o4[j]);   // don't evict input from L3
    }
}

extern "C" void kernel_launch(void* const* d_in, const int* in_sizes, int n_in,
                              void* d_out, int out_size, void* d_ws, size_t ws_size,
                              hipStream_t stream) {
    const float* scores = (const float*)d_in[0];
    float* out = (float*)d_out;
    const int B = in_sizes[0] / V_DIM;
    const int NBLK1 = B * CPB;

    char* wsb = (char*)d_ws;
    uint2*     cand   = (uint2*)wsb;                       // NBLK1*CAPB*8 B = 1 MB @ B=256
    size_t off = (size_t)NBLK1 * CAPB * sizeof(uint2);
    unsigned*  cnts   = (unsigned*)(wsb + off);            // NBLK1*4 B
    off += (size_t)NBLK1 * sizeof(unsigned);
    off = (off + 15) & ~(size_t)15;
    double*    psum   = (double*)(wsb + off);              // NBLK1*8 B
    off += (size_t)NBLK1 * sizeof(double);
    off = (off + 15) & ~(size_t)15;
    unsigned*  rowctr = (unsigned*)(wsb + off);            // B*4 B (never reset; mod-CPB)
    off += (size_t)B * sizeof(unsigned);
    off = (off + 15) & ~(size_t)15;
    RowParams* params = (RowParams*)(wsb + off);           // B*16 B

    hipLaunchKernelGGL(k1_scan_select, dim3(NBLK1), dim3(K1T), 0, stream,
                       scores, cand, cnts, psum, rowctr, params);
    hipLaunchKernelGGL(k3_write, dim3(32, B), dim3(256), 0, stream,
                       scores, params, out);
}

// Round 6
// 73.463 us; speedup vs baseline: 6.2788x; 6.2788x over previous
//
#include <hip/hip_runtime.h>

#define V_DIM 128000
#define NV4 (V_DIM / 4)             // 32000
#define K_TOP 50
#define BLK 1024
#define NWAVE (BLK / 64)            // 16
#define CAP 1024                    // candidate cap (E[n]=173, sigma~13)
#define NBINS 2048
#define THRESH 3.0f                 // P(N(0,1)>3)=1.35e-3 -> E[n]=173 >> 50

typedef float floatx4 __attribute__((ext_vector_type(4)));

__device__ __forceinline__ unsigned key_of(float x) {
    unsigned b = __float_as_uint(x);
    return b ^ (unsigned)((((int)b) >> 31) | 0x80000000);
}
__device__ __forceinline__ float val_of(unsigned u) {
    unsigned b = u ^ (unsigned)(((~(int)u) >> 31) | 0x80000000);
    return __uint_as_float(b);
}

__global__ __launch_bounds__(BLK, 1)
void topk_softmax_fused(const float* __restrict__ x, float* __restrict__ out) {
    __shared__ unsigned cu_[CAP];
    __shared__ unsigned ci_[CAP];
    __shared__ unsigned hist[NBINS];    // fallback only
    __shared__ double   wsum[NWAVE];
    __shared__ double   msum[NWAVE];
    __shared__ unsigned s_cnt, s_thr, s_b1;
    __shared__ int      s_e, s_idxcut;
    __shared__ float    s_lnS;

    const int t = threadIdx.x;
    const int row = blockIdx.x;
    const float4* __restrict__ x4 = (const float4*)(x + (size_t)row * V_DIM);

    if (t == 0) s_cnt = 0;
    __syncthreads();

    // ---- pass 1: stream read; exp partial; collect candidates > THRESH ----
    float lsum = 0.f;
    for (int j = t; j < NV4; j += BLK) {
        float4 v = x4[j];
        lsum += __expf(v.x) + __expf(v.y) + __expf(v.z) + __expf(v.w);
        if (v.x > THRESH) { unsigned p = atomicAdd(&s_cnt, 1u); if (p < CAP) { cu_[p] = key_of(v.x); ci_[p] = 4u * j; } }
        if (v.y > THRESH) { unsigned p = atomicAdd(&s_cnt, 1u); if (p < CAP) { cu_[p] = key_of(v.y); ci_[p] = 4u * j + 1u; } }
        if (v.z > THRESH) { unsigned p = atomicAdd(&s_cnt, 1u); if (p < CAP) { cu_[p] = key_of(v.z); ci_[p] = 4u * j + 2u; } }
        if (v.w > THRESH) { unsigned p = atomicAdd(&s_cnt, 1u); if (p < CAP) { cu_[p] = key_of(v.w); ci_[p] = 4u * j + 3u; } }
    }
    #pragma unroll
    for (int off = 32; off; off >>= 1) lsum += __shfl_down(lsum, off);
    if ((t & 63) == 0) wsum[t >> 6] = (double)lsum;   // fixed slots -> deterministic
    __syncthreads();
    unsigned n = s_cnt;

    if (n < (unsigned)K_TOP || n > (unsigned)CAP) {
        // ---- exact fallback (never taken for N(0,1)): full-row histogram select ----
        for (int i = t; i < NBINS; i += BLK) hist[i] = 0;
        if (t == 0) s_cnt = 0;
        __syncthreads();
        for (int j = t; j < NV4; j += BLK) {
            float4 v = x4[j];
            atomicAdd(&hist[key_of(v.x) >> 21], 1u);
            atomicAdd(&hist[key_of(v.y) >> 21], 1u);
            atomicAdd(&hist[key_of(v.z) >> 21], 1u);
            atomicAdd(&hist[key_of(v.w) >> 21], 1u);
        }
        __syncthreads();
        if (t == 0) {
            unsigned cum = 0; int b1 = 0;
            for (int b = NBINS - 1; b >= 0; --b) {
                if (cum + hist[b] >= (unsigned)K_TOP) { b1 = b; break; }
                cum += hist[b];
            }
            s_b1 = (unsigned)b1;
        }
        __syncthreads();
        const unsigned kmin = s_b1 << 21;    // bins >= b1 contain the whole top-K
        for (int j = t; j < NV4; j += BLK) {
            float4 v = x4[j];
            unsigned u0 = key_of(v.x), u1 = key_of(v.y), u2 = key_of(v.z), u3 = key_of(v.w);
            if (u0 >= kmin) { unsigned p = atomicAdd(&s_cnt, 1u); if (p < CAP) { cu_[p] = u0; ci_[p] = 4u * j; } }
            if (u1 >= kmin) { unsigned p = atomicAdd(&s_cnt, 1u); if (p < CAP) { cu_[p] = u1; ci_[p] = 4u * j + 1u; } }
            if (u2 >= kmin) { unsigned p = atomicAdd(&s_cnt, 1u); if (p < CAP) { cu_[p] = u2; ci_[p] = 4u * j + 2u; } }
            if (u3 >= kmin) { unsigned p = atomicAdd(&s_cnt, 1u); if (p < CAP) { cu_[p] = u3; ci_[p] = 4u * j + 3u; } }
        }
        __syncthreads();
        n = (s_cnt < (unsigned)CAP) ? s_cnt : (unsigned)CAP;
    }
    __syncthreads();

    // ---- exact rank-K select among cu_[0..n) (contains all of top-K) ----
    for (int j = t; j < (int)n; j += BLK) {
        unsigned uj = cu_[j]; int g = 0, eq = 0;
        for (int k = 0; k < (int)n; ++k) {
            unsigned uk = cu_[k];
            g += (uk > uj) ? 1 : 0;
            eq += (uk == uj) ? 1 : 0;
        }
        if (g < K_TOP && K_TOP <= g + eq) { s_thr = uj; s_e = K_TOP - g; }
    }
    __syncthreads();
    const unsigned thr = s_thr; const int e = s_e;
    // e-th smallest index among ties (jax top_k masks lowest indices first)
    for (int j = t; j < (int)n; j += BLK) {
        if (cu_[j] == thr) {
            int ij = (int)ci_[j], rank = 0;
            for (int k = 0; k < (int)n; ++k)
                rank += (cu_[k] == thr && (int)ci_[k] < ij) ? 1 : 0;
            if (rank == e - 1) s_idxcut = ij;
        }
    }
    __syncthreads();
    const int idxcut = s_idxcut;
    // masked-sum (double) and S = sum(exp) - masked
    double ms = 0.0;
    for (int j = t; j < (int)n; j += BLK) {
        unsigned u = cu_[j];
        if (u > thr || (u == thr && (int)ci_[j] <= idxcut))
            ms += exp((double)val_of(u));
    }
    #pragma unroll
    for (int off = 32; off; off >>= 1) ms += __shfl_down(ms, off);
    if ((t & 63) == 0) msum[t >> 6] = ms;
    __syncthreads();
    if (t == 0) {
        double S = 0.0;
        for (int w = 0; w < NWAVE; ++w) S += wsum[w];   // fixed order
        for (int w = 0; w < NWAVE; ++w) S -= msum[w];
        s_lnS = (float)log(S);
    }
    __syncthreads();

    // ---- pass 2: masked softmax write (L3-hot re-read, nt stores) ----
    const float lnS = s_lnS;
    const float thrv = val_of(thr);
    const bool use_f = (thrv != 0.0f);     // uniform branch; +-0 uses key compare
    floatx4* __restrict__ o4 = (floatx4*)(out + (size_t)row * V_DIM);
    for (int j = t; j < NV4; j += BLK) {
        float4 v = x4[j];
        const int i0 = 4 * j;
        bool m0, m1, m2, m3;
        if (use_f) {
            m0 = (v.x > thrv) || (v.x == thrv && i0 <= idxcut);
            m1 = (v.y > thrv) || (v.y == thrv && i0 + 1 <= idxcut);
            m2 = (v.z > thrv) || (v.z == thrv && i0 + 2 <= idxcut);
            m3 = (v.w > thrv) || (v.w == thrv && i0 + 3 <= idxcut);
        } else {
            unsigned u0 = key_of(v.x), u1 = key_of(v.y), u2 = key_of(v.z), u3 = key_of(v.w);
            m0 = (u0 > thr) || (u0 == thr && i0 <= idxcut);
            m1 = (u1 > thr) || (u1 == thr && i0 + 1 <= idxcut);
            m2 = (u2 > thr) || (u2 == thr && i0 + 2 <= idxcut);
            m3 = (u3 > thr) || (u3 == thr && i0 + 3 <= idxcut);
        }
        floatx4 o;
        o.x = m0 ? 0.f : __expf(v.x - lnS);
        o.y = m1 ? 0.f : __expf(v.y - lnS);
        o.z = m2 ? 0.f : __expf(v.z - lnS);
        o.w = m3 ? 0.f : __expf(v.w - lnS);
        __builtin_nontemporal_store(o, &o4[j]);   // keep input L3-resident
    }
}

extern "C" void kernel_launch(void* const* d_in, const int* in_sizes, int n_in,
                              void* d_out, int out_size, void* d_ws, size_t ws_size,
                              hipStream_t stream) {
    const float* scores = (const float*)d_in[0];
    float* out = (float*)d_out;
    const int B = in_sizes[0] / V_DIM;
    hipLaunchKernelGGL(topk_softmax_fused, dim3(B), dim3(BLK), 0, stream,
                       scores, out);
}